// Round 4
// baseline (205.715 us; speedup 1.0000x reference)
//
#include <hip/hip_runtime.h>

#define N_NODES 100000
#define N_EDGES 640000
#define F 128

typedef __attribute__((ext_vector_type(8))) short short8;
typedef __attribute__((ext_vector_type(4))) float float4v;

// RNE float -> bf16 bits
static __device__ __forceinline__ unsigned short f2bf(float f) {
    unsigned int u = __float_as_uint(f);
    u += 0x7fffu + ((u >> 16) & 1u);
    return (unsigned short)(u >> 16);
}

// ---------------------------------------------------------------------------
// Kernel 0: transpose+convert W1 (fp32 [256][128]) into Wt bf16 [256][128]:
//   Wt[n][k] = W1[(n&128)+k][n&127]
// n<128 rows = A-half (W1[k][n]); n>=128 = B-half. 64 KB, stays L2-hot.
// ---------------------------------------------------------------------------
__global__ __launch_bounds__(256) void prep_wt(
    const float* __restrict__ W1, unsigned short* __restrict__ Wt)
{
    int id = blockIdx.x * 256 + threadIdx.x;       // 0 .. 32767
    int n = id >> 7, k = id & 127;
    float v = W1[((n & 128) + k) * 128 + (n & 127)];
    Wt[id] = f2bf(v);
}

// ---------------------------------------------------------------------------
// Kernel 1: node projections via bf16 MFMA.
//   y=0: A[m][n] = sum_k h[m][k]*W1[k][n] + b1[n]   (bf16 out)
//   y=1: B[m][n] = sum_k h[m][k]*W1[128+k][n]       (bf16 out)
// 256 threads (4 waves), M-tile=64 nodes, N=128, K=128 in one pass.
// Wave w owns cols [w*32, w*32+32).
// B-fragments loaded DIRECTLY from global Wt (bf16, L2-hot, no LDS stage);
// verified equivalent to the round-2 LDS-staged indexing:
//   bfrag[j][k0][t] = Wt[y*128 + n0w + j*16 + l16][k0*32 + quad*8 + t]
// Only the h tile goes through LDS (needed for the A-frag transpose).
// LDS = 17.4 KB -> occupancy VGPR-limited (~4 blocks/CU vs 3 with w_lds).
// ---------------------------------------------------------------------------
__global__ __launch_bounds__(256) void node_proj(
    const float* __restrict__ h, const unsigned short* __restrict__ Wt,
    const float* __restrict__ b1,
    unsigned short* __restrict__ A, unsigned short* __restrict__ B)
{
    __shared__ unsigned short h_lds[64 * 136];    // 17.4 KB

    const int tid   = threadIdx.x;
    const int y     = blockIdx.y;
    const int node0 = blockIdx.x * 64;
    const int lane  = tid & 63;
    const int l16   = lane & 15;
    const int quad  = lane >> 4;
    const int w     = tid >> 6;
    const int n0w   = w * 32;

    // ---- B-fragments straight from Wt (issued first; L2-hot 64 KB) ----
    short8 bfrag[2][4];
#pragma unroll
    for (int j = 0; j < 2; ++j) {
        const unsigned short* wrow =
            Wt + (size_t)(y * 128 + n0w + j * 16 + l16) * F + quad * 8;
#pragma unroll
        for (int k0 = 0; k0 < 4; ++k0)
            bfrag[j][k0] = *(const short8*)(wrow + k0 * 32);
    }

    // ---- stage h tile: 64 rows x 128 fp32 -> bf16 in LDS ----
#pragma unroll
    for (int i = 0; i < 8; ++i) {
        int idx = i * 256 + tid;                  // float4 index, 0..2047
        int m = idx >> 5, c4 = idx & 31;
        int row_g = node0 + m; if (row_g >= N_NODES) row_g = N_NODES - 1;
        float4 v = *(const float4*)(h + (size_t)row_g * F + c4 * 4);
        uint2 p;
        p.x = (unsigned)f2bf(v.x) | ((unsigned)f2bf(v.y) << 16);
        p.y = (unsigned)f2bf(v.z) | ((unsigned)f2bf(v.w) << 16);
        *(uint2*)&h_lds[m * 136 + c4 * 4] = p;
    }
    __syncthreads();

    float4v acc[4][2];
#pragma unroll
    for (int i = 0; i < 4; ++i)
#pragma unroll
        for (int j = 0; j < 2; ++j) acc[i][j] = (float4v){0.f, 0.f, 0.f, 0.f};

#pragma unroll
    for (int k0 = 0; k0 < 4; ++k0) {
        short8 af[4];
#pragma unroll
        for (int i = 0; i < 4; ++i)
            af[i] = *(const short8*)&h_lds[(i * 16 + l16) * 136 + k0 * 32 + quad * 8];
#pragma unroll
        for (int i = 0; i < 4; ++i)
#pragma unroll
            for (int j = 0; j < 2; ++j)
                acc[i][j] = __builtin_amdgcn_mfma_f32_16x16x32_bf16(
                    af[i], bfrag[j][k0], acc[i][j], 0, 0, 0);
    }

    unsigned short* outp = (y == 0) ? A : B;
#pragma unroll
    for (int j = 0; j < 2; ++j) {
        int col = n0w + j * 16 + l16;
        float bias = (y == 0) ? b1[col] : 0.f;
#pragma unroll
        for (int i = 0; i < 4; ++i) {
#pragma unroll
            for (int r = 0; r < 4; ++r) {
                int row_g = node0 + i * 16 + quad * 4 + r;
                if (row_g < N_NODES)
                    outp[(size_t)row_g * F + col] = f2bf(acc[i][j][r] + bias);
            }
        }
    }
}

// ---------------------------------------------------------------------------
// Kernel 2: per-edge score from bf16 A,B. ONE edge per thread:
//   score[e] = b2 + sum_{j=0}^{127} relu(A[src,j]+B[dst,j]) * W2[j]
// A row = 128 bf16 = SIXTEEN uint4 chunks (c < 16 — round-3 bug was c < 8,
// which dropped channels 64..127). W2 float4 index 2c,2c+1 covers all 32.
// Index loads + out stores fully coalesced; W2 thread-uniform (scalar path).
// ---------------------------------------------------------------------------
__global__ __launch_bounds__(256) void edge_score(
    const unsigned short* __restrict__ A, const unsigned short* __restrict__ B,
    const int* __restrict__ src, const int* __restrict__ dst,
    const float* __restrict__ W2, const float* __restrict__ b2,
    float* __restrict__ out)
{
    const int e = blockIdx.x * 256 + threadIdx.x;
    const int s = src[e];
    const int d = dst[e];
    const uint4* Ap = (const uint4*)(A + (size_t)s * F);
    const uint4* Bp = (const uint4*)(B + (size_t)d * F);

    float sacc = 0.f;
#define TERM(UA, UB, WL, WH)                                                   \
    {                                                                          \
        float fa0 = __uint_as_float((UA) << 16);                               \
        float fa1 = __uint_as_float((UA) & 0xFFFF0000u);                       \
        float fb0 = __uint_as_float((UB) << 16);                               \
        float fb1 = __uint_as_float((UB) & 0xFFFF0000u);                       \
        sacc = fmaf(fmaxf(fa0 + fb0, 0.f), (WL), sacc);                        \
        sacc = fmaf(fmaxf(fa1 + fb1, 0.f), (WH), sacc);                        \
    }
#pragma unroll
    for (int c = 0; c < 16; ++c) {                 // 16 x 8 = all 128 channels
        uint4 av = Ap[c];
        uint4 bv = Bp[c];
        float4 wlo = ((const float4*)W2)[c * 2 + 0];   // W2[c*8 .. c*8+3]
        float4 whi = ((const float4*)W2)[c * 2 + 1];   // W2[c*8+4 .. c*8+7]
        TERM(av.x, bv.x, wlo.x, wlo.y)
        TERM(av.y, bv.y, wlo.z, wlo.w)
        TERM(av.z, bv.z, whi.x, whi.y)
        TERM(av.w, bv.w, whi.z, whi.w)
    }
#undef TERM

    out[e] = sacc + b2[0];
}

extern "C" void kernel_launch(void* const* d_in, const int* in_sizes, int n_in,
                              void* d_out, int out_size, void* d_ws, size_t ws_size,
                              hipStream_t stream) {
    const float* h   = (const float*)d_in[0];
    const int*   src = (const int*)d_in[1];
    const int*   dst = (const int*)d_in[2];
    const float* W1  = (const float*)d_in[3];
    const float* b1  = (const float*)d_in[4];
    const float* W2  = (const float*)d_in[5];
    const float* b2  = (const float*)d_in[6];
    float* out = (float*)d_out;

    // workspace layout (bf16): Wt[256][128] | A[100000][128] | B[100000][128]
    unsigned short* Wt = (unsigned short*)d_ws;
    unsigned short* A  = Wt + 256 * 128;
    unsigned short* B  = A + (size_t)N_NODES * F;

    prep_wt<<<128, 256, 0, stream>>>(W1, Wt);
    node_proj<<<dim3((N_NODES + 63) / 64, 2), 256, 0, stream>>>(h, Wt, b1, A, B);
    edge_score<<<N_EDGES / 256, 256, 0, stream>>>(A, B, src, dst, W2, b2, out);
}

// Round 5
// 177.488 us; speedup vs baseline: 1.1590x; 1.1590x over previous
//
#include <hip/hip_runtime.h>

#define N_NODES 100000
#define N_EDGES 640000
#define F 128

typedef __attribute__((ext_vector_type(8))) short short8;
typedef __attribute__((ext_vector_type(4))) float float4v;

// RNE float -> bf16 bits
static __device__ __forceinline__ unsigned short f2bf(float f) {
    unsigned int u = __float_as_uint(f);
    u += 0x7fffu + ((u >> 16) & 1u);
    return (unsigned short)(u >> 16);
}

// ---------------------------------------------------------------------------
// Kernel 0: transpose+convert W1 (fp32 [256][128]) into Wt bf16 [256][128]:
//   Wt[n][k] = W1[(n&128)+k][n&127]
// n<128 rows = A-half (W1[k][n]); n>=128 = B-half. 64 KB, stays L2-hot.
// ---------------------------------------------------------------------------
__global__ __launch_bounds__(256) void prep_wt(
    const float* __restrict__ W1, unsigned short* __restrict__ Wt)
{
    int id = blockIdx.x * 256 + threadIdx.x;       // 0 .. 32767
    int n = id >> 7, k = id & 127;
    float v = W1[((n & 128) + k) * 128 + (n & 127)];
    Wt[id] = f2bf(v);
}

// ---------------------------------------------------------------------------
// Kernel 1: node projections via bf16 MFMA. (unchanged from round 4)
//   y=0: A[m][n] = sum_k h[m][k]*W1[k][n] + b1[n]   (bf16 out)
//   y=1: B[m][n] = sum_k h[m][k]*W1[128+k][n]       (bf16 out)
// ---------------------------------------------------------------------------
__global__ __launch_bounds__(256) void node_proj(
    const float* __restrict__ h, const unsigned short* __restrict__ Wt,
    const float* __restrict__ b1,
    unsigned short* __restrict__ A, unsigned short* __restrict__ B)
{
    __shared__ unsigned short h_lds[64 * 136];    // 17.4 KB

    const int tid   = threadIdx.x;
    const int y     = blockIdx.y;
    const int node0 = blockIdx.x * 64;
    const int lane  = tid & 63;
    const int l16   = lane & 15;
    const int quad  = lane >> 4;
    const int w     = tid >> 6;
    const int n0w   = w * 32;

    // ---- B-fragments straight from Wt (L2-hot 64 KB, no LDS stage) ----
    short8 bfrag[2][4];
#pragma unroll
    for (int j = 0; j < 2; ++j) {
        const unsigned short* wrow =
            Wt + (size_t)(y * 128 + n0w + j * 16 + l16) * F + quad * 8;
#pragma unroll
        for (int k0 = 0; k0 < 4; ++k0)
            bfrag[j][k0] = *(const short8*)(wrow + k0 * 32);
    }

    // ---- stage h tile: 64 rows x 128 fp32 -> bf16 in LDS ----
#pragma unroll
    for (int i = 0; i < 8; ++i) {
        int idx = i * 256 + tid;                  // float4 index, 0..2047
        int m = idx >> 5, c4 = idx & 31;
        int row_g = node0 + m; if (row_g >= N_NODES) row_g = N_NODES - 1;
        float4 v = *(const float4*)(h + (size_t)row_g * F + c4 * 4);
        uint2 p;
        p.x = (unsigned)f2bf(v.x) | ((unsigned)f2bf(v.y) << 16);
        p.y = (unsigned)f2bf(v.z) | ((unsigned)f2bf(v.w) << 16);
        *(uint2*)&h_lds[m * 136 + c4 * 4] = p;
    }
    __syncthreads();

    float4v acc[4][2];
#pragma unroll
    for (int i = 0; i < 4; ++i)
#pragma unroll
        for (int j = 0; j < 2; ++j) acc[i][j] = (float4v){0.f, 0.f, 0.f, 0.f};

#pragma unroll
    for (int k0 = 0; k0 < 4; ++k0) {
        short8 af[4];
#pragma unroll
        for (int i = 0; i < 4; ++i)
            af[i] = *(const short8*)&h_lds[(i * 16 + l16) * 136 + k0 * 32 + quad * 8];
#pragma unroll
        for (int i = 0; i < 4; ++i)
#pragma unroll
            for (int j = 0; j < 2; ++j)
                acc[i][j] = __builtin_amdgcn_mfma_f32_16x16x32_bf16(
                    af[i], bfrag[j][k0], acc[i][j], 0, 0, 0);
    }

    unsigned short* outp = (y == 0) ? A : B;
#pragma unroll
    for (int j = 0; j < 2; ++j) {
        int col = n0w + j * 16 + l16;
        float bias = (y == 0) ? b1[col] : 0.f;
#pragma unroll
        for (int i = 0; i < 4; ++i) {
#pragma unroll
            for (int r = 0; r < 4; ++r) {
                int row_g = node0 + i * 16 + quad * 4 + r;
                if (row_g < N_NODES)
                    outp[(size_t)row_g * F + col] = f2bf(acc[i][j][r] + bias);
            }
        }
    }
}

// ---------------------------------------------------------------------------
// Kernel 2: per-edge score from bf16 A,B.
// GROUPED LANES (minimal unique-lines/instruction) + 4-edge ILP:
//   8 lanes per edge, each lane covers 16 channels (2x uint4 per array);
//   each 8-lane group processes 4 consecutive edges -> 16 independent
//   16B gathers per thread in flight. Round-4's 1-edge/thread layout made
//   every instruction touch 64 unique lines (75 us, latency-bound even with
//   warm cache); this restores 8-lines/instr and quadruples MLP vs round 2.
// ---------------------------------------------------------------------------
__global__ __launch_bounds__(256) void edge_score(
    const unsigned short* __restrict__ A, const unsigned short* __restrict__ B,
    const int* __restrict__ src, const int* __restrict__ dst,
    const float* __restrict__ W2, const float* __restrict__ b2,
    float* __restrict__ out)
{
    const int tid = threadIdx.x;
    const int sub = tid & 7;                      // lane within edge-group
    const int e0  = blockIdx.x * 128 + (tid >> 3) * 4;   // 4 edges per group
    const int j0  = sub * 16;

    // indices: one int4 per thread (e0 is 4-aligned), broadcast within group
    const int4 sv = *(const int4*)(src + e0);
    const int4 dv = *(const int4*)(dst + e0);
    const int s[4] = {sv.x, sv.y, sv.z, sv.w};
    const int d[4] = {dv.x, dv.y, dv.z, dv.w};

    // issue all 16 gathers up front
    uint4 av0[4], av1[4], bv0[4], bv1[4];
#pragma unroll
    for (int i = 0; i < 4; ++i) {
        const uint4* Ap = (const uint4*)(A + (size_t)s[i] * F + j0);
        const uint4* Bp = (const uint4*)(B + (size_t)d[i] * F + j0);
        av0[i] = Ap[0]; av1[i] = Ap[1];
        bv0[i] = Bp[0]; bv1[i] = Bp[1];
    }

    // W2 fragment for this lane's 16 channels (reused across 4 edges)
    const float4* Wp = (const float4*)(W2 + j0);
    const float4 w0 = Wp[0], w1 = Wp[1], w2 = Wp[2], w3 = Wp[3];
    const float bias = b2[0];

#define TERM(UA, UB, WL, WH)                                                   \
    {                                                                          \
        float fa0 = __uint_as_float((UA) << 16);                               \
        float fa1 = __uint_as_float((UA) & 0xFFFF0000u);                       \
        float fb0 = __uint_as_float((UB) << 16);                               \
        float fb1 = __uint_as_float((UB) & 0xFFFF0000u);                       \
        sacc = fmaf(fmaxf(fa0 + fb0, 0.f), (WL), sacc);                        \
        sacc = fmaf(fmaxf(fa1 + fb1, 0.f), (WH), sacc);                        \
    }
#pragma unroll
    for (int i = 0; i < 4; ++i) {
        float sacc = 0.f;
        TERM(av0[i].x, bv0[i].x, w0.x, w0.y)
        TERM(av0[i].y, bv0[i].y, w0.z, w0.w)
        TERM(av0[i].z, bv0[i].z, w1.x, w1.y)
        TERM(av0[i].w, bv0[i].w, w1.z, w1.w)
        TERM(av1[i].x, bv1[i].x, w2.x, w2.y)
        TERM(av1[i].y, bv1[i].y, w2.z, w2.w)
        TERM(av1[i].z, bv1[i].z, w3.x, w3.y)
        TERM(av1[i].w, bv1[i].w, w3.z, w3.w)
        sacc += __shfl_xor(sacc, 1);
        sacc += __shfl_xor(sacc, 2);
        sacc += __shfl_xor(sacc, 4);
        if (sub == 0) out[e0 + i] = sacc + bias;
    }
#undef TERM
}

extern "C" void kernel_launch(void* const* d_in, const int* in_sizes, int n_in,
                              void* d_out, int out_size, void* d_ws, size_t ws_size,
                              hipStream_t stream) {
    const float* h   = (const float*)d_in[0];
    const int*   src = (const int*)d_in[1];
    const int*   dst = (const int*)d_in[2];
    const float* W1  = (const float*)d_in[3];
    const float* b1  = (const float*)d_in[4];
    const float* W2  = (const float*)d_in[5];
    const float* b2  = (const float*)d_in[6];
    float* out = (float*)d_out;

    // workspace layout (bf16): Wt[256][128] | A[100000][128] | B[100000][128]
    unsigned short* Wt = (unsigned short*)d_ws;
    unsigned short* A  = Wt + 256 * 128;
    unsigned short* B  = A + (size_t)N_NODES * F;

    prep_wt<<<128, 256, 0, stream>>>(W1, Wt);
    node_proj<<<dim3((N_NODES + 63) / 64, 2), 256, 0, stream>>>(h, Wt, b1, A, B);
    edge_score<<<N_EDGES / 128, 256, 0, stream>>>(A, B, src, dst, W2, b2, out);
}